// Round 2
// baseline (282.332 us; speedup 1.0000x reference)
//
#include <hip/hip_runtime.h>

// LSTM B=4096, S=512, INPUT=1, HIDDEN=20 + linear head.
// R2 mapping: ONE chain per 64-lane wave, gate computation split across
// half-waves: lanes 0..19 ("if-half") compute gates (i,f) packed as float2,
// lanes 32..51 ("go-half") compute (g,o). Each lane holds only 20 float2
// W_hh weights (40 VGPRs) -> registers stay resident, <=128 VGPR -> 4
// waves/SIMD (4096 waves total) to hide the serial per-step latency.
// Gate math in v_pk_fma_f32; sigmoid & tanh unified as fma(m, rcp(1+exp2(a)), k)
// with lane-constant (m,k) so both halves share one instruction stream.
// h(t-1) broadcast = whole-wave single-address ds_read_b128 (conflict-free);
// g,o cross halves via 2 ds_bpermute. x is wave-uniform -> scalar loads.
// Head (h . W_lin) deferred per 16-step chunk; W_lin uniform -> SGPRs.

#define BATCH 4096
#define SLEN  512
#define H     20
#define CHUNK 16
#define LOG2E 1.44269504088896340736f

typedef float v2f __attribute__((ext_vector_type(2)));

__device__ __forceinline__ float fexp2(float x) { return __builtin_amdgcn_exp2f(x); }
__device__ __forceinline__ float frcp(float x)  { return __builtin_amdgcn_rcpf(x); }
__device__ __forceinline__ v2f  mk2(float a, float b) { v2f r; r.x = a; r.y = b; return r; }
__device__ __forceinline__ v2f  pkfma(v2f a, v2f b, v2f c) { return __builtin_elementwise_fma(a, b, c); }

__global__ __launch_bounds__(256, 4) void lstm_fused(
    const float* __restrict__ x,      // [B, S, 1]
    const float* __restrict__ W_ih,   // [80, 1]
    const float* __restrict__ W_hh,   // [80, 20]
    const float* __restrict__ b_ih,   // [80]
    const float* __restrict__ b_hh,   // [80]
    const float* __restrict__ W_lin,  // [1, 20]
    const float* __restrict__ b_lin,  // [1]
    float* __restrict__ out)          // [B, S, 1]
{
    __shared__ __align__(16) float hbuf[4][CHUNK][H];  // per-warp h ring

    const int tid  = threadIdx.x;
    const int w    = __builtin_amdgcn_readfirstlane(tid >> 6); // warp in block
    const int lane = tid & 63;
    const int half = (lane >> 5) & 1;   // 0 = (i,f) half, 1 = (g,o) half
    const int jr   = lane & 31;         // unit index within half (0..19 valid)
    const int j    = jr < H ? jr : H - 1;  // clamped for pad lanes
    const bool unitLane = (jr < H);
    const long b = (long)blockIdx.x * 4 + w;   // chain id (4096 exactly)

    const float s1 = -LOG2E;          // sigmoid pre-scale
    const float s2 = -2.0f * LOG2E;   // tanh pre-scale

    // this lane's two gate rows: half0 -> (i:j, f:H+j); half1 -> (g:2H+j, o:3H+j)
    const int   r0  = half ? (2 * H + j) : j;
    const int   r1  = half ? (3 * H + j) : (H + j);
    const float sc0 = half ? s2 : s1;
    const float sc1 = s1;
    const v2f m2 = half ? mk2(2.0f, 1.0f) : mk2(1.0f, 1.0f);
    const v2f k2 = half ? mk2(-1.0f, 0.0f) : mk2(0.0f, 0.0f);

    // 20 float2 recurrent weights per lane (40 VGPRs), pre-scaled
    v2f w2[H];
#pragma unroll
    for (int k = 0; k < H; ++k)
        w2[k] = mk2(sc0 * W_hh[r0 * H + k], sc1 * W_hh[r1 * H + k]);
    const v2f b2  = mk2(sc0 * (b_ih[r0] + b_hh[r0]), sc1 * (b_ih[r1] + b_hh[r1]));
    const v2f xw2 = mk2(sc0 * W_ih[r0], sc1 * W_ih[r1]);
    const float blin = b_lin[0];

    const float* xb = x + b * SLEN;    // wave-uniform
    float*       ob = out + b * SLEN;

    const int paddr = (lane ^ 32) * 4; // partner lane byte addr for bpermute

    if (!half && unitLane) hbuf[w][CHUNK - 1][j] = 0.0f;  // h(-1) = 0
    float c = 0.0f;

#pragma unroll 1
    for (int T = 0; T < SLEN; T += CHUNK) {
        float xs[CHUNK];               // wave-uniform -> SGPRs via s_load
#pragma unroll
        for (int i = 0; i < CHUNK; ++i) xs[i] = xb[T + i];

#pragma unroll
        for (int i = 0; i < CHUNK; ++i) {
            const int rp = (i + CHUNK - 1) & (CHUNK - 1);
            const float* hrow = &hbuf[w][rp][0];
            // two accumulator chains to halve FMA dep latency
            v2f aA = pkfma(mk2(xs[i], xs[i]), xw2, b2);
            v2f aB = mk2(0.0f, 0.0f);
#pragma unroll
            for (int k4 = 0; k4 < 5; ++k4) {
                const float4 h4 = *(const float4*)(hrow + 4 * k4); // wave broadcast
                v2f* acc0 = (k4 < 2) ? &aA : &aB;
                v2f* acc1 = (k4 < 2) ? &aA : &aB;
                *acc0 = pkfma(mk2(h4.x, h4.x), w2[4 * k4 + 0], *acc0);
                *acc1 = pkfma(mk2(h4.y, h4.y), w2[4 * k4 + 1], *acc1);
                *acc0 = pkfma(mk2(h4.z, h4.z), w2[4 * k4 + 2], *acc0);
                *acc1 = pkfma(mk2(h4.w, h4.w), w2[4 * k4 + 3], *acc1);
            }
            const v2f a2 = aA + aB;
            // unified activation: res = m * rcp(1 + exp2(a)) + k
            const v2f e2 = mk2(fexp2(a2.x), fexp2(a2.y));
            const v2f d2 = e2 + mk2(1.0f, 1.0f);
            const v2f p2 = mk2(frcp(d2.x), frcp(d2.y));
            const v2f res = pkfma(m2, p2, k2);
            // if-half: res=(i,f). pull g,o from partner lane (go-half: garbage)
            const float gg = __int_as_float(__builtin_amdgcn_ds_bpermute(paddr, __float_as_int(res.x)));
            const float oo = __int_as_float(__builtin_amdgcn_ds_bpermute(paddr, __float_as_int(res.y)));
            c = fmaf(res.y, c, res.x * gg);
            const float tc = fmaf(2.0f, frcp(1.0f + fexp2(s2 * c)), -1.0f);
            const float h = oo * tc;
            if (!half && unitLane) hbuf[w][i][j] = h;  // banks j..j+19, no conflict
        }

        // deferred head: if-half lanes 0..15 reduce one stored row each
        if (!half && jr < CHUNK) {
            const float* hr = &hbuf[w][jr][0];
            v2f y2 = mk2(blin, 0.0f);
#pragma unroll
            for (int k = 0; k < 10; ++k) {
                const v2f h2 = mk2(hr[2 * k], hr[2 * k + 1]);
                const v2f wl = mk2(W_lin[2 * k], W_lin[2 * k + 1]); // uniform -> SGPR
                y2 = pkfma(h2, wl, y2);
            }
            ob[T + jr] = y2.x + y2.y;   // coalesced 16-float burst
        }
    }
}

extern "C" void kernel_launch(void* const* d_in, const int* in_sizes, int n_in,
                              void* d_out, int out_size, void* d_ws, size_t ws_size,
                              hipStream_t stream) {
    const float* x     = (const float*)d_in[0];
    const float* W_ih  = (const float*)d_in[1];
    const float* W_hh  = (const float*)d_in[2];
    const float* b_ih  = (const float*)d_in[3];
    const float* b_hh  = (const float*)d_in[4];
    const float* W_lin = (const float*)d_in[5];
    const float* b_lin = (const float*)d_in[6];
    float* out = (float*)d_out;

    lstm_fused<<<BATCH / 4, 256, 0, stream>>>(x, W_ih, W_hh, b_ih, b_hh,
                                              W_lin, b_lin, out);
}

// Round 3
// 229.016 us; speedup vs baseline: 1.2328x; 1.2328x over previous
//
#include <hip/hip_runtime.h>

// LSTM B=4096, S=512, INPUT=1, HIDDEN=20 + linear head.
// R3: R1's mapping (3 chains per 64-lane wave, lane = (chain, unit), all 4
// gates per lane) with fp16 data halving every cost:
//  - W_hh rows as packed half2, gates via v_dot2_f32_f16 (fp32 acc): 40 dot2
//    instead of 80 fma per lane-step; 50 weight VGPRs instead of 100+ (R1's
//    AGPR round-trips gone).
//  - h ring buffer in LDS as fp16: per-step broadcast read = 2xb128+1xb64 =
//    2560 B/wave-step (20 LDS-bus cyc for 3 chains) vs R2's 5120 B for 1.
//  - group stride 200 words => group offsets mod 32 = {0,8,16,24}: the 4
//    sub-broadcast addresses hit disjoint bank quads (R1 had 4-way conflicts).
// Sigmoid/tanh via pre-scaled accumulators: sigmoid = rcp(1+exp2(a)).
// Head deferred per 16-step chunk -> coalesced 16-float store per chain.

#define BATCH 4096
#define SLEN  512
#define H     20
#define CHUNK 16
#define LOG2E 1.44269504088896340736f
#define GSTRIDE 200   // words per group LDS region (16 rows * 12 + 8 pad)
#define RSTRIDE 12    // words per h row (10 half2 used + 2 pad)

typedef _Float16 h2 __attribute__((ext_vector_type(2)));

__device__ __forceinline__ float fexp2(float x) { return __builtin_amdgcn_exp2f(x); }
__device__ __forceinline__ float frcp(float x)  { return __builtin_amdgcn_rcpf(x); }
__device__ __forceinline__ h2 bch2(unsigned int u) { return __builtin_bit_cast(h2, u); }

__global__ __launch_bounds__(64, 4) void lstm_fused(
    const float* __restrict__ x,      // [B, S, 1]
    const float* __restrict__ W_ih,   // [80, 1]
    const float* __restrict__ W_hh,   // [80, 20]
    const float* __restrict__ b_ih,   // [80]
    const float* __restrict__ b_hh,   // [80]
    const float* __restrict__ W_lin,  // [1, 20]
    const float* __restrict__ b_lin,  // [1]
    float* __restrict__ out)          // [B, S, 1]
{
    __shared__ __align__(16) unsigned int hw[4 * GSTRIDE];  // h ring, fp16
    __shared__ float xbuf[4][CHUNK];
    _Float16* hh = (_Float16*)hw;

    const int lane = threadIdx.x;           // 0..63
    int grp = lane / H;                     // 0..3 (3 = dummy group)
    const int j = lane - grp * H;           // 0..19 (0..3 for dummy)
    const long b = (long)blockIdx.x * 3 + grp;
    const bool valid = (grp < 3) && (b < BATCH);
    const long bc = valid ? b : 0;

    const float s1 = -LOG2E;          // sigmoid pre-scale
    const float s2 = -2.0f * LOG2E;   // tanh pre-scale

    // ---- per-lane weights: 4 gate rows x 10 half2 (40 VGPRs), pre-scaled ----
    h2 w2[4][10];
    float bb[4], xw[4];
#pragma unroll
    for (int g = 0; g < 4; ++g) {
        const int row = g * H + j;
        const float sc = (g == 2) ? s2 : s1;   // torch gate order i,f,g,o
#pragma unroll
        for (int k = 0; k < 10; ++k) {
            h2 t;
            t.x = (_Float16)(sc * W_hh[row * H + 2 * k]);
            t.y = (_Float16)(sc * W_hh[row * H + 2 * k + 1]);
            w2[g][k] = t;
        }
        bb[g] = sc * (b_ih[row] + b_hh[row]);
        xw[g] = sc * W_ih[row];
    }
    h2 wl2[10];
#pragma unroll
    for (int k = 0; k < 10; ++k) {
        h2 t;
        t.x = (_Float16)W_lin[2 * k];
        t.y = (_Float16)W_lin[2 * k + 1];
        wl2[k] = t;
    }
    const float blin = b_lin[0];

    const float* xb = x + bc * SLEN;
    float*       ob = out + bc * SLEN;

    const int gbase = grp * GSTRIDE;
    // h(-1) = 0 in ring row CHUNK-1
    hh[2 * (gbase + (CHUNK - 1) * RSTRIDE) + j] = (_Float16)0.0f;
    float c = 0.0f;

#pragma unroll 1
    for (int T = 0; T < SLEN; T += CHUNK) {
        if (j < CHUNK) xbuf[grp][j] = xb[T + j];   // coalesced x chunk -> LDS

#pragma unroll
        for (int i = 0; i < CHUNK; ++i) {
            const int rp = (i + CHUNK - 1) & (CHUNK - 1);
            const int base = gbase + rp * RSTRIDE;
            const float xt = xbuf[grp][i];          // group broadcast (2-way: free)
            // h(t-1) row: 20 fp16 = words 0..9 -> b128 + b128 + b64
            const uint4 A = *(const uint4*)&hw[base];
            const uint4 B = *(const uint4*)&hw[base + 4];
            const uint2 C = *(const uint2*)&hw[base + 8];
            const unsigned int pw[10] = {A.x, A.y, A.z, A.w,
                                         B.x, B.y, B.z, B.w, C.x, C.y};
            float a[4];
#pragma unroll
            for (int g = 0; g < 4; ++g) a[g] = fmaf(xt, xw[g], bb[g]);
#pragma unroll
            for (int k = 0; k < 10; ++k) {
#pragma unroll
                for (int g = 0; g < 4; ++g)   // 4 independent dep chains
                    a[g] = __builtin_amdgcn_fdot2(bch2(pw[k]), w2[g][k], a[g], false);
            }
            // activations: pre-scaled, so sigmoid = rcp(1+exp2(a))
            const float gi = frcp(1.0f + fexp2(a[0]));
            const float gf = frcp(1.0f + fexp2(a[1]));
            const float gg = fmaf(2.0f, frcp(1.0f + fexp2(a[2])), -1.0f); // tanh
            const float go = frcp(1.0f + fexp2(a[3]));
            c = fmaf(gf, c, gi * gg);
            const float tc = fmaf(2.0f, frcp(1.0f + fexp2(s2 * c)), -1.0f);
            const float hval = go * tc;
            hh[2 * (gbase + i * RSTRIDE) + j] = (_Float16)hval;  // ds_write_b16
        }

        // ---- deferred head: lanes j<16 reduce one stored row each ----
        if (j < CHUNK) {
            const int rb = gbase + j * RSTRIDE;
            const uint4 A = *(const uint4*)&hw[rb];
            const uint4 B = *(const uint4*)&hw[rb + 4];
            const uint2 C = *(const uint2*)&hw[rb + 8];
            const unsigned int pw[10] = {A.x, A.y, A.z, A.w,
                                         B.x, B.y, B.z, B.w, C.x, C.y};
            float y = blin;
#pragma unroll
            for (int k = 0; k < 10; ++k)
                y = __builtin_amdgcn_fdot2(bch2(pw[k]), wl2[k], y, false);
            if (valid) ob[T + j] = y;   // coalesced 16-float burst per chain
        }
    }
}

extern "C" void kernel_launch(void* const* d_in, const int* in_sizes, int n_in,
                              void* d_out, int out_size, void* d_ws, size_t ws_size,
                              hipStream_t stream) {
    const float* x     = (const float*)d_in[0];
    const float* W_ih  = (const float*)d_in[1];
    const float* W_hh  = (const float*)d_in[2];
    const float* b_ih  = (const float*)d_in[3];
    const float* b_hh  = (const float*)d_in[4];
    const float* W_lin = (const float*)d_in[5];
    const float* b_lin = (const float*)d_in[6];
    float* out = (float*)d_out;

    const int nblocks = (BATCH + 2) / 3;  // 3 chains per 64-thread wave/block
    lstm_fused<<<nblocks, 64, 0, stream>>>(x, W_ih, W_hh, b_ih, b_hh,
                                           W_lin, b_lin, out);
}